// Round 6
// baseline (336.480 us; speedup 1.0000x reference)
//
#include <hip/hip_runtime.h>

// MADE flow: u = (x - m)*exp(-a), logdet = -sum(a)
// B=524288, NI=32, H=128, NC=64.
// R8: LDS-free. R4 (100us) was the best point; R5's bigger waves spilled and
// regressed. R4's remaining structural serialization: per-block 48KB LDS
// stage + the post-L1 __syncthreads (full vmcnt drain, re-phases all 4 waves
// every block). Weights are only 72KB and L2/L1-resident; LDS added no needed
// bandwidth. This round ALL layers read weight fragments from global wf
// (like L1 already did): no __shared__, no stage, no barrier -> waves fully
// independent, free de-phasing, one wave's MFMA hides another's act-load
// latency. Same K=32/nt=2 dataflow, bounds(256,3) = 170-reg no-spill budget.

#define B_ROWS 524288
#define NI 32
#define HD 128
#define NC 64

// K=32 fragments: 1 frag = 16(j) x 32(k) f16 = 512 halfs = 1KB
#define L2_BASE 24    // L1 frags: 8 jt * 3 kt = 24
#define L3_BASE 56    // L2 frags: 8 jt * 4 kt = 32
#define N_FRAGS 72    // L3 frags: 4 jt * 4 kt = 16

typedef _Float16 half8 __attribute__((ext_vector_type(8)));
typedef float f32x4 __attribute__((ext_vector_type(4)));

__device__ inline f32x4 relu4(f32x4 v) {
  v[0] = fmaxf(v[0], 0.f); v[1] = fmaxf(v[1], 0.f);
  v[2] = fmaxf(v[2], 0.f); v[3] = fmaxf(v[3], 0.f);
  return v;
}

__device__ inline half8 cvt8(f32x4 lo, f32x4 hi) {
  half8 h;
  h[0] = (_Float16)lo[0]; h[1] = (_Float16)lo[1];
  h[2] = (_Float16)lo[2]; h[3] = (_Float16)lo[3];
  h[4] = (_Float16)hi[0]; h[5] = (_Float16)hi[1];
  h[6] = (_Float16)hi[2]; h[7] = (_Float16)hi[3];
  return h;
}

// ---------------- prep: masked f16 weights in K=32 MFMA-A fragment order ----
// Fragment (frag, lane) holds A[m][k]: m = jt*16 + (lane&15),
// k = kt*32 + (e>>2)*16 + (lane>>4)*4 + (e&3)  (e=0..7, two stacked K=16
// halves). Stored at wf[frag*512 + lane*8 + e].
__global__ void prep_weights(const float* __restrict__ W1, const float* __restrict__ Wc,
                             const float* __restrict__ W2, const float* __restrict__ W3,
                             _Float16* __restrict__ wf) {
  int tid = blockIdx.x * blockDim.x + threadIdx.x;
  if (tid >= N_FRAGS * 64) return;
  int frag = tid >> 6;
  int lane = tid & 63;
  int q = lane >> 4, c = lane & 15;
  int L, jt, kt;
  if (frag < L2_BASE)      { L = 0; jt = frag / 3;              kt = frag % 3; }
  else if (frag < L3_BASE) { L = 1; jt = (frag - L2_BASE) >> 2; kt = (frag - L2_BASE) & 3; }
  else                     { L = 2; jt = (frag - L3_BASE) >> 2; kt = (frag - L3_BASE) & 3; }
  int j = jt * 16 + c;  // output unit (row of W)
  half8 v;
#pragma unroll
  for (int e = 0; e < 8; ++e) {
    int k = kt * 32 + (e >> 2) * 16 + q * 4 + (e & 3);
    float w;
    if (L == 0) {
      // layer1 K-dim is [x(32) | cond(64)]; mask m1 = (j%31 >= k), Wc unmasked
      if (k < NI) w = ((j % 31) >= k) ? W1[j * NI + k] : 0.f;
      else        w = Wc[j * NC + (k - NI)];
    } else if (L == 1) {
      w = ((j % 31) >= (k % 31)) ? W2[j * HD + k] : 0.f;          // m2
    } else {
      w = (((j % 32) - 1) >= (k % 31)) ? W3[j * HD + k] : 0.f;    // m3
    }
    v[e] = (_Float16)w;
  }
  *(half8*)(wf + (size_t)tid * 8) = v;
}

// ---------------- fused main kernel ----------------
// 4 waves/block, each wave owns 32 batch rows (nt = 2 tiles of 16), fully
// independent (no LDS, no barrier). Grid = B/(4*32) = 4096 blocks.
// launch_bounds(256,3): 170-reg budget, no spill; 12 waves/CU (reg-capped).
__global__ __launch_bounds__(256, 3) void made_fused(
    const float* __restrict__ x, const float* __restrict__ cond,
    const float* __restrict__ b1, const float* __restrict__ b2,
    const float* __restrict__ b3, const _Float16* __restrict__ wf,
    float* __restrict__ out) {
  const int tid  = threadIdx.x;
  const int lane = tid & 63;
  const int wid  = tid >> 6;
  const int q = lane >> 4, c = lane & 15;
  const long rowbase = ((long)blockIdx.x * 4 + wid) * 32;

  // ---- activation loads first; x kept LIVE to the epilogue ----
  f32x4 xv[2][2], cv[2][4];
#pragma unroll
  for (int nt = 0; nt < 2; ++nt) {
    const f32x4* xr = (const f32x4*)(x    + (rowbase + nt * 16 + c) * NI);
    const f32x4* cr = (const f32x4*)(cond + (rowbase + nt * 16 + c) * NC);
    xv[nt][0] = xr[q];     xv[nt][1] = xr[4 + q];
    cv[nt][0] = cr[q];     cv[nt][1] = cr[4 + q];
    cv[nt][2] = cr[8 + q]; cv[nt][3] = cr[12 + q];
  }

  // ---- B-fragments for layer 1 (K=96 over [x|cond])
  half8 bf[3][2];
#pragma unroll
  for (int nt = 0; nt < 2; ++nt) {
    bf[0][nt] = cvt8(xv[nt][0], xv[nt][1]);
    bf[1][nt] = cvt8(cv[nt][0], cv[nt][1]);
    bf[2][nt] = cvt8(cv[nt][2], cv[nt][3]);
  }

  // ---- layer 1: 8 jt x 3 kt32, weights from global (L1/L2-resident).
  // jh-split keeps the live acc file at 32 regs.
  f32x4 acc[4][2];
  half8 h1[4][2];
#pragma unroll
  for (int jh = 0; jh < 2; ++jh) {
#pragma unroll
    for (int j4 = 0; j4 < 4; ++j4) {
      f32x4 bv = *(const f32x4*)(b1 + (jh * 4 + j4) * 16 + q * 4);
      acc[j4][0] = bv; acc[j4][1] = bv;
    }
#pragma unroll
    for (int j4 = 0; j4 < 4; ++j4) {
      int jt = jh * 4 + j4;
#pragma unroll
      for (int kt = 0; kt < 3; ++kt) {
        half8 a = *(const half8*)(wf + (((jt * 3 + kt) * 64 + lane) << 3));
#pragma unroll
        for (int nt = 0; nt < 2; ++nt)
          acc[j4][nt] = __builtin_amdgcn_mfma_f32_16x16x32_f16(a, bf[kt][nt], acc[j4][nt], 0, 0, 0);
      }
    }
    // C/D tile pair (2p, 2p+1) == lower/upper K=16 halves of next-layer B frag
#pragma unroll
    for (int p = 0; p < 2; ++p)
#pragma unroll
      for (int nt = 0; nt < 2; ++nt)
        h1[jh * 2 + p][nt] = cvt8(relu4(acc[p * 2][nt]), relu4(acc[p * 2 + 1][nt]));
  }

  // ---- layer 2: 8 jt x 4 kt32, weights from global
  half8 h2[4][2];
#pragma unroll
  for (int jh = 0; jh < 2; ++jh) {
#pragma unroll
    for (int j4 = 0; j4 < 4; ++j4) {
      f32x4 bv = *(const f32x4*)(b2 + (jh * 4 + j4) * 16 + q * 4);
      acc[j4][0] = bv; acc[j4][1] = bv;
    }
#pragma unroll
    for (int j4 = 0; j4 < 4; ++j4) {
      int jt = jh * 4 + j4;
#pragma unroll
      for (int kt = 0; kt < 4; ++kt) {
        half8 a = *(const half8*)(wf + (((L2_BASE + jt * 4 + kt) * 64 + lane) << 3));
#pragma unroll
        for (int nt = 0; nt < 2; ++nt)
          acc[j4][nt] = __builtin_amdgcn_mfma_f32_16x16x32_f16(a, h1[kt][nt], acc[j4][nt], 0, 0, 0);
      }
    }
#pragma unroll
    for (int p = 0; p < 2; ++p)
#pragma unroll
      for (int nt = 0; nt < 2; ++nt)
        h2[jh * 2 + p][nt] = cvt8(relu4(acc[p * 2][nt]), relu4(acc[p * 2 + 1][nt]));
  }

  // ---- layer 3: 4 jt x 4 kt32, weights from global; acc[0..1]=m_, [2..3]=a
#pragma unroll
  for (int jt = 0; jt < 4; ++jt) {
    f32x4 bv = *(const f32x4*)(b3 + jt * 16 + q * 4);
    acc[jt][0] = bv; acc[jt][1] = bv;
  }
#pragma unroll
  for (int jt = 0; jt < 4; ++jt)
#pragma unroll
    for (int kt = 0; kt < 4; ++kt) {
      half8 a = *(const half8*)(wf + (((L3_BASE + jt * 4 + kt) * 64 + lane) << 3));
#pragma unroll
      for (int nt = 0; nt < 2; ++nt)
        acc[jt][nt] = __builtin_amdgcn_mfma_f32_16x16x32_f16(a, h2[kt][nt], acc[jt][nt], 0, 0, 0);
    }

  // ---- epilogue: lane owns batch row m = rowbase+nt*16+c; x is still live.
#pragma unroll
  for (int nt = 0; nt < 2; ++nt) {
    long m = rowbase + nt * 16 + c;
    f32x4 xa = xv[nt][0], xb = xv[nt][1];
    f32x4 mva = acc[0][nt], mvb = acc[1][nt];
    f32x4 ava = acc[2][nt], avb = acc[3][nt];
    f32x4 ua, ub;
    float s = 0.f;
#pragma unroll
    for (int i = 0; i < 4; ++i) {
      float aa = fminf(fmaxf(ava[i], -5.f), 5.f);
      float ab = fminf(fmaxf(avb[i], -5.f), 5.f);
      ua[i] = (xa[i] - mva[i]) * __expf(-aa);
      ub[i] = (xb[i] - mvb[i]) * __expf(-ab);
      s += aa + ab;
    }
    *(f32x4*)(out + m * NI + q * 4) = ua;
    *(f32x4*)(out + m * NI + 16 + q * 4) = ub;
    s += __shfl_xor(s, 16);
    s += __shfl_xor(s, 32);
    if (q == 0) out[(long)B_ROWS * NI + m] = -s;  // logdet
  }
}

extern "C" void kernel_launch(void* const* d_in, const int* in_sizes, int n_in,
                              void* d_out, int out_size, void* d_ws, size_t ws_size,
                              hipStream_t stream) {
  const float* x    = (const float*)d_in[0];
  const float* cond = (const float*)d_in[1];
  const float* W1   = (const float*)d_in[2];
  const float* b1   = (const float*)d_in[3];
  const float* Wc   = (const float*)d_in[4];
  const float* W2   = (const float*)d_in[5];
  const float* b2   = (const float*)d_in[6];
  const float* W3   = (const float*)d_in[7];
  const float* b3   = (const float*)d_in[8];
  _Float16* wf = (_Float16*)d_ws;  // 72 frags * 512 halfs * 2B = 72 KB

  prep_weights<<<(N_FRAGS * 64 + 255) / 256, 256, 0, stream>>>(W1, Wc, W2, W3, wf);
  made_fused<<<B_ROWS / 128, 256, 0, stream>>>(x, cond, b1, b2, b3, wf, (float*)d_out);
}

// Round 7
// 300.693 us; speedup vs baseline: 1.1190x; 1.1190x over previous
//
#include <hip/hip_runtime.h>

// MADE flow: u = (x - m)*exp(-a), logdet = -sum(a)
// B=524288, NI=32, H=128, NC=64.
// R9: 32x32x16 MFMA everywhere. Wave's 32 rows = one N=32 tile -> 72 MFMAs
// (was 144), half the issue/chain depth, same FLOPs/loads. C/D->next-B is
// register-direct: D regs0..7 = kt-even B-frag, regs8..15 = kt-odd (from
// verified 32x32 C/D layout). Live set shrinks (acc pair = 32 regs, peak
// ~122): with bounds(256,3) the allocator may land <=128 -> HW packs 4
// waves/SIMD (R6 proved bounds don't cap occupancy). LDS = L2 weights only
// (32KB -> 4-5 blocks/CU by LDS); L1 (24KB) + L3 (16KB) weights from global
// (phase-local ~L1$-sized working set, NOT R6's 72KB thrash).

#define B_ROWS 524288
#define NI 32
#define HD 128
#define NC 64

// 32x32x16 A-frags: 1 frag = 32(j) x 16(k) f16 = 512 halfs = 1KB
#define L2_BASE 24    // L1 frags: 4 jt * 6 kt = 24
#define L3_BASE 56    // L2 frags: 4 jt * 8 kt = 32
#define N_FRAGS 72    // L3 frags: 2 jt * 8 kt = 16

typedef _Float16 half8 __attribute__((ext_vector_type(8)));
typedef float f32x4 __attribute__((ext_vector_type(4)));
typedef float f32x16 __attribute__((ext_vector_type(16)));

__device__ inline f32x4 relu4(f32x4 v) {
  v[0] = fmaxf(v[0], 0.f); v[1] = fmaxf(v[1], 0.f);
  v[2] = fmaxf(v[2], 0.f); v[3] = fmaxf(v[3], 0.f);
  return v;
}

__device__ inline half8 cvt8(f32x4 lo, f32x4 hi) {
  half8 h;
  h[0] = (_Float16)lo[0]; h[1] = (_Float16)lo[1];
  h[2] = (_Float16)lo[2]; h[3] = (_Float16)lo[3];
  h[4] = (_Float16)hi[0]; h[5] = (_Float16)hi[1];
  h[6] = (_Float16)hi[2]; h[7] = (_Float16)hi[3];
  return h;
}

// D (f32x16) -> two next-layer B-frags with relu. Regs 0..7 = kt-even frag
// (k_local = 4h+{0..3} then 8+4h+{0..3}), regs 8..15 = kt-odd frag.
#define CVTQ2(D0, D1, A) do {                                                 \
    f32x4 t0, t1, t2, t3;                                                     \
    t0[0]=A[0]; t0[1]=A[1]; t0[2]=A[2]; t0[3]=A[3];                           \
    t1[0]=A[4]; t1[1]=A[5]; t1[2]=A[6]; t1[3]=A[7];                           \
    t2[0]=A[8]; t2[1]=A[9]; t2[2]=A[10]; t2[3]=A[11];                         \
    t3[0]=A[12]; t3[1]=A[13]; t3[2]=A[14]; t3[3]=A[15];                       \
    D0 = cvt8(relu4(t0), relu4(t1));                                          \
    D1 = cvt8(relu4(t2), relu4(t3));                                          \
  } while (0)

// C init from bias: D row m = (reg&3) + 8*(reg>>2) + 4*hh.
#define BIAS16(A, BP, BASE) do {                                              \
    f32x4 q0 = *(const f32x4*)((BP) + (BASE) + 4 * hh);                       \
    f32x4 q1 = *(const f32x4*)((BP) + (BASE) + 4 * hh + 8);                   \
    f32x4 q2 = *(const f32x4*)((BP) + (BASE) + 4 * hh + 16);                  \
    f32x4 q3 = *(const f32x4*)((BP) + (BASE) + 4 * hh + 24);                  \
    A[0]=q0[0]; A[1]=q0[1]; A[2]=q0[2]; A[3]=q0[3];                           \
    A[4]=q1[0]; A[5]=q1[1]; A[6]=q1[2]; A[7]=q1[3];                           \
    A[8]=q2[0]; A[9]=q2[1]; A[10]=q2[2]; A[11]=q2[3];                         \
    A[12]=q3[0]; A[13]=q3[1]; A[14]=q3[2]; A[15]=q3[3];                       \
  } while (0)

// ---------------- prep: masked f16 weights in 32x32x16 MFMA-A order --------
// Fragment (frag, lane) holds A[m][k]: m = jt*32 + (lane&31),
// k = kt*16 + (lane>>5)*4 + (e&3) + 8*(e>>2)  (two stacked K=8 halves).
// Stored at wf[frag*512 + lane*8 + e].
__global__ void prep_weights(const float* __restrict__ W1, const float* __restrict__ Wc,
                             const float* __restrict__ W2, const float* __restrict__ W3,
                             _Float16* __restrict__ wf) {
  int tid = blockIdx.x * blockDim.x + threadIdx.x;
  if (tid >= N_FRAGS * 64) return;
  int frag = tid >> 6;
  int lane = tid & 63;
  int hh = lane >> 5, nn = lane & 31;
  int L, jt, kt;
  if (frag < L2_BASE)      { L = 0; jt = frag / 6;              kt = frag % 6; }
  else if (frag < L3_BASE) { L = 1; jt = (frag - L2_BASE) >> 3; kt = (frag - L2_BASE) & 7; }
  else                     { L = 2; jt = (frag - L3_BASE) >> 3; kt = (frag - L3_BASE) & 7; }
  int j = jt * 32 + nn;  // output unit (row of W)
  half8 v;
#pragma unroll
  for (int e = 0; e < 8; ++e) {
    int k = kt * 16 + hh * 4 + (e & 3) + 8 * (e >> 2);
    float w;
    if (L == 0) {
      // layer1 K-dim is [x(32) | cond(64)]; mask m1 = (j%31 >= k), Wc unmasked
      if (k < NI) w = ((j % 31) >= k) ? W1[j * NI + k] : 0.f;
      else        w = Wc[j * NC + (k - NI)];
    } else if (L == 1) {
      w = ((j % 31) >= (k % 31)) ? W2[j * HD + k] : 0.f;          // m2
    } else {
      w = (((j % 32) - 1) >= (k % 31)) ? W3[j * HD + k] : 0.f;    // m3
    }
    v[e] = (_Float16)w;
  }
  *(half8*)(wf + (size_t)tid * 8) = v;
}

// ---------------- fused main kernel ----------------
// 4 waves/block, each wave owns 32 batch rows (one 32-wide N tile).
// Grid = B/(4*32) = 4096 blocks. bounds(256,3): 170-reg budget (no forced
// spill); actual alloc target ~122 -> HW may pack 4 waves/SIMD.
__global__ __launch_bounds__(256, 3) void made_fused(
    const float* __restrict__ x, const float* __restrict__ cond,
    const float* __restrict__ b1, const float* __restrict__ b2,
    const float* __restrict__ b3, const _Float16* __restrict__ wf,
    float* __restrict__ out) {
  // ONLY L2-layer weights staged in LDS: frags 24..55 -> 32 * 1KB = 32KB
  __shared__ __align__(16) _Float16 wlds[32 * 512];

  const int tid  = threadIdx.x;
  const int lane = tid & 63;
  const int wid  = tid >> 6;
  const int hh = lane >> 5, nn = lane & 31;
  const long r = ((long)blockIdx.x * 4 + wid) * 32 + nn;  // this lane's row

  // ---- activation loads FIRST (oldest vmcnt entries; bf cvt won't drain
  // the LDS stage). xv0..3 stay LIVE to the epilogue (x[r][4hh+8g+i]).
  const f32x4* xr = (const f32x4*)(x + r * NI);
  const f32x4* cr = (const f32x4*)(cond + r * NC);
  f32x4 xv0 = xr[hh],     xv1 = xr[2 + hh], xv2 = xr[4 + hh], xv3 = xr[6 + hh];
  f32x4 cv0 = cr[hh],     cv1 = cr[2 + hh], cv2 = cr[4 + hh], cv3 = cr[6 + hh];
  f32x4 cv4 = cr[8 + hh], cv5 = cr[10 + hh], cv6 = cr[12 + hh], cv7 = cr[14 + hh];

  // ---- stage L2 weights (32KB) via global_load_lds, 8KB per wave ----
  {
    const char* gsrc = (const char*)wf + L2_BASE * 1024 + wid * 8192;
    char* ldst = (char*)wlds + wid * 8192;
#pragma unroll
    for (int i = 0; i < 8; ++i) {
      __builtin_amdgcn_global_load_lds(
          (const __attribute__((address_space(1))) void*)(gsrc + i * 1024 + lane * 16),
          (__attribute__((address_space(3))) void*)(ldst + i * 1024),
          16, 0, 0);
    }
  }

  // ---- B-fragments for layer 1: K=96 over [x|cond], 6 K16-frags ----
  half8 bf[6];
  bf[0] = cvt8(xv0, xv1); bf[1] = cvt8(xv2, xv3);
  bf[2] = cvt8(cv0, cv1); bf[3] = cvt8(cv2, cv3);
  bf[4] = cvt8(cv4, cv5); bf[5] = cvt8(cv6, cv7);

  // ---- layer 1: 4 jt-tiles x 6 kt, weights from GLOBAL (24KB, L1$-resident;
  // overlaps the LDS stage). jt-pairs keep acc at 32 regs.
  half8 hf1[8];
#pragma unroll
  for (int p = 0; p < 2; ++p) {
    f32x16 A0, A1;
    BIAS16(A0, b1, (2 * p) * 32);
    BIAS16(A1, b1, (2 * p + 1) * 32);
#pragma unroll
    for (int kt = 0; kt < 6; ++kt) {
      half8 w0 = *(const half8*)(wf + ((((2 * p) * 6 + kt) * 64 + lane) << 3));
      half8 w1 = *(const half8*)(wf + ((((2 * p + 1) * 6 + kt) * 64 + lane) << 3));
      A0 = __builtin_amdgcn_mfma_f32_32x32x16_f16(w0, bf[kt], A0, 0, 0, 0);
      A1 = __builtin_amdgcn_mfma_f32_32x32x16_f16(w1, bf[kt], A1, 0, 0, 0);
    }
    CVTQ2(hf1[4 * p + 0], hf1[4 * p + 1], A0);
    CVTQ2(hf1[4 * p + 2], hf1[4 * p + 3], A1);
  }

  __syncthreads();  // LDS weights ready; L2 reads hit LDS

  // ---- layer 2: 4 jt-tiles x 8 kt, weights from LDS ----
  half8 hf2[8];
#pragma unroll
  for (int p = 0; p < 2; ++p) {
    f32x16 A0, A1;
    BIAS16(A0, b2, (2 * p) * 32);
    BIAS16(A1, b2, (2 * p + 1) * 32);
#pragma unroll
    for (int kt = 0; kt < 8; ++kt) {
      half8 w0 = *(const half8*)(wlds + ((((2 * p) * 8 + kt) * 64 + lane) << 3));
      half8 w1 = *(const half8*)(wlds + ((((2 * p + 1) * 8 + kt) * 64 + lane) << 3));
      A0 = __builtin_amdgcn_mfma_f32_32x32x16_f16(w0, hf1[kt], A0, 0, 0, 0);
      A1 = __builtin_amdgcn_mfma_f32_32x32x16_f16(w1, hf1[kt], A1, 0, 0, 0);
    }
    CVTQ2(hf2[4 * p + 0], hf2[4 * p + 1], A0);
    CVTQ2(hf2[4 * p + 2], hf2[4 * p + 3], A1);
  }

  // ---- layer 3: 2 jt-tiles (m_, a) x 8 kt, weights from GLOBAL (16KB) ----
  f32x16 Am, Aa;
  BIAS16(Am, b3, 0);
  BIAS16(Aa, b3, 32);
#pragma unroll
  for (int kt = 0; kt < 8; ++kt) {
    half8 wm = *(const half8*)(wf + (((56 + kt) * 64 + lane) << 3));
    half8 wa = *(const half8*)(wf + (((64 + kt) * 64 + lane) << 3));
    Am = __builtin_amdgcn_mfma_f32_32x32x16_f16(wm, hf2[kt], Am, 0, 0, 0);
    Aa = __builtin_amdgcn_mfma_f32_32x32x16_f16(wa, hf2[kt], Aa, 0, 0, 0);
  }

  // ---- epilogue: lane owns row r, units 4hh+8g+{0..3}; x still live ----
  float s = 0.f;
#pragma unroll
  for (int g = 0; g < 4; ++g) {
    f32x4 xg = (g == 0) ? xv0 : (g == 1) ? xv1 : (g == 2) ? xv2 : xv3;
    f32x4 u;
#pragma unroll
    for (int i = 0; i < 4; ++i) {
      float aa = fminf(fmaxf(Aa[4 * g + i], -5.f), 5.f);
      u[i] = (xg[i] - Am[4 * g + i]) * __expf(-aa);
      s += aa;
    }
    *(f32x4*)(out + r * NI + 4 * hh + 8 * g) = u;
  }
  s += __shfl_xor(s, 32);
  if (hh == 0) out[(long)B_ROWS * NI + r] = -s;  // logdet
}

extern "C" void kernel_launch(void* const* d_in, const int* in_sizes, int n_in,
                              void* d_out, int out_size, void* d_ws, size_t ws_size,
                              hipStream_t stream) {
  const float* x    = (const float*)d_in[0];
  const float* cond = (const float*)d_in[1];
  const float* W1   = (const float*)d_in[2];
  const float* b1   = (const float*)d_in[3];
  const float* Wc   = (const float*)d_in[4];
  const float* W2   = (const float*)d_in[5];
  const float* b2   = (const float*)d_in[6];
  const float* W3   = (const float*)d_in[7];
  const float* b3   = (const float*)d_in[8];
  _Float16* wf = (_Float16*)d_ws;  // 72 frags * 512 halfs * 2B = 72 KB

  prep_weights<<<(N_FRAGS * 64 + 255) / 256, 256, 0, stream>>>(W1, Wc, W2, W3, wf);
  made_fused<<<B_ROWS / 128, 256, 0, stream>>>(x, cond, b1, b2, b3, wf, (float*)d_out);
}